// Round 3
// baseline (366.999 us; speedup 1.0000x reference)
//
#include <hip/hip_runtime.h>

typedef __attribute__((ext_vector_type(8))) short short8;
typedef __attribute__((ext_vector_type(4))) float f32x4;

__device__ __forceinline__ unsigned short f2bf(float f) {
  unsigned u = __float_as_uint(f);
  u += 0x7FFF + ((u >> 16) & 1);
  return (unsigned short)(u >> 16);
}
__device__ __forceinline__ float bf2f(unsigned short h) {
  return __uint_as_float(((unsigned)h) << 16);
}

// ---------------- kernel 1: entire MLP, one block ----------------
// h1(256x64) -> h2(256x64) -> hbar(64) -> Mf(768), all in LDS, no atomics.
__global__ __launch_bounds__(1024) void mlp_all_kernel(
    const float* __restrict__ w1, const float* __restrict__ b1,
    const float* __restrict__ w2, const float* __restrict__ b2,
    const float* __restrict__ w3, const float* __restrict__ b3,
    float* __restrict__ wsM, float* __restrict__ outMf)
{
  __shared__ float W2T[64 * 65];     // W2T[j*65+k] = W2[k][j]
  __shared__ float h1s[128][64];     // half the coords at a time
  __shared__ float partial[16][64];
  __shared__ float hbar[64];
  const int t = threadIdx.x;
  const int k = t & 63;
  const int rg = t >> 6;  // 0..15

  for (int idx = t; idx < 4096; idx += 1024) {
    int kk = idx >> 6, j = idx & 63;
    W2T[j * 65 + kk] = w2[idx];
  }

  float ssum = 0.f;
  for (int m = 0; m < 2; ++m) {
    __syncthreads();  // W2T ready (m=0); h1s consumed (m=1)
    for (int idx = t; idx < 8192; idx += 1024) {
      int rl = idx >> 6, j = idx & 63;
      int r = m * 128 + rl;
      float gx = (float)(r >> 4) * (1.0f / 15.0f);
      float gy = (float)(r & 15) * (1.0f / 15.0f);
      h1s[rl][j] = fmaxf(gx * w1[2 * j] + gy * w1[2 * j + 1] + b1[j], 0.f);
    }
    __syncthreads();
    float acc[8] = {0, 0, 0, 0, 0, 0, 0, 0};
    for (int j = 0; j < 64; ++j) {
      float w = W2T[j * 65 + k];
#pragma unroll
      for (int rr = 0; rr < 8; ++rr) acc[rr] += h1s[rg * 8 + rr][j] * w;
    }
    float b2v = b2[k];
#pragma unroll
    for (int rr = 0; rr < 8; ++rr) ssum += fmaxf(acc[rr] + b2v, 0.f);
  }
  partial[rg][k] = ssum;
  __syncthreads();
  if (t < 64) {
    float s = 0.f;
#pragma unroll
    for (int g = 0; g < 16; ++g) s += partial[g][t];
    hbar[t] = s;
  }
  __syncthreads();

  // out layer: one wave per j, lane-parallel dot + shuffle reduce
  const int wv = t >> 6;
  float hv = hbar[k];
  for (int j = wv; j < 768; j += 16) {
    float v = hv * w3[j * 64 + k];
#pragma unroll
    for (int off = 32; off > 0; off >>= 1) v += __shfl_xor(v, off);
    if (k == 0) {
      float o = b3[j] + v * (1.0f / 256.0f);
      float mm = 1.0f / (1.0f + expf(-o));
      wsM[j] = mm;
      outMf[j] = mm;
    }
  }
}

// ---------------- kernel 2: build fused per-channel operator T ----------------
// recon_vec = T_c . patch_vec  (256x256 per channel, bf16)
__global__ __launch_bounds__(1024) void build_T_kernel(
    const float* __restrict__ wsM, unsigned short* __restrict__ wsT)
{
  __shared__ float Dl[16][16];
  __shared__ float Ml[256];
  __shared__ float Gl[16][16][16];
  const int t = threadIdx.x;
  const int c = blockIdx.x >> 1;
  const int bh = blockIdx.x & 1;

  if (t < 256) {
    int i = t >> 4, k = t & 15;
    float sc = (i == 0) ? 0.25f : 0.35355339059327373f;
    Dl[i][k] = sc * cosf(3.14159265358979323846f * (float)((2 * i + 1) * k) * (1.0f / 32.0f));
    Ml[t] = wsM[c * 256 + t];
  }
  __syncthreads();

  for (int e = t; e < 4096; e += 1024) {
    int i = e >> 8, ss = (e >> 4) & 15, v = e & 15;
    float g = 0.f;
#pragma unroll
    for (int l = 0; l < 16; ++l)
      g += Ml[i * 16 + l] * Dl[l][ss] * Dl[l][v];
    Gl[i][ss][v] = g;
  }
  __syncthreads();

  const int oc = bh * 128 + (t >> 3);
  const int jsel = t & 7;
  const int r = oc >> 4, ss = oc & 15;
  const int j0 = jsel * 2, j1 = j0 + 1;
  float a0[16], a1[16];
#pragma unroll
  for (int k = 0; k < 16; ++k) { a0[k] = 0.f; a1[k] = 0.f; }
  for (int i = 0; i < 16; ++i) {
    float wr = Dl[i][r];
    float G16[16];
    const float* gp = &Gl[i][ss][0];
#pragma unroll
    for (int k = 0; k < 16; ++k) G16[k] = gp[k];
    float w0 = wr * Dl[i][j0];
    float w1v = wr * Dl[i][j1];
#pragma unroll
    for (int k = 0; k < 16; ++k) { a0[k] += w0 * G16[k]; a1[k] += w1v * G16[k]; }
  }
  unsigned short* dst = wsT + (size_t)c * 65536 + (size_t)oc * 256;
  unsigned* d0 = (unsigned*)(dst + j0 * 16);
  unsigned* d1 = (unsigned*)(dst + j1 * 16);
#pragma unroll
  for (int k = 0; k < 8; ++k)
    d0[k] = (unsigned)f2bf(a0[2 * k]) | ((unsigned)f2bf(a0[2 * k + 1]) << 16);
#pragma unroll
  for (int k = 0; k < 8; ++k)
    d1[k] = (unsigned)f2bf(a1[2 * k]) | ((unsigned)f2bf(a1[2 * k + 1]) << 16);
}

// ---------------- main kernel: streaming GEMM, 1 barrier per strip ----------------
// grid 510 x 512. Triple-buffered A (bf16 patches) + double-buffered R (f32 recon)
// => every LDS hazard is covered by the single per-strip barrier.
// T-slice (32 outcols x 256 K) in 64 VGPR/wave. Loads for strip i+2 issued at top
// of iter i (MFMA+stash+scatter between issue and the draining barrier).
__global__ __launch_bounds__(512, 4) void gemm_main_kernel(
    const float* __restrict__ x, const unsigned short* __restrict__ wsT,
    float* __restrict__ out)
{
  __shared__ f32x4 smemv[3584];  // 56 KB: A[3][8K] @0, R[2][16K] @24576
  unsigned char* S8 = (unsigned char*)smemv;
  const int t = threadIdx.x;
  const int lane = t & 63;
  const int w = t >> 6;        // wave id = outcol group (32 cols each)
  const int p = lane & 15;     // A-row (outcol low) AND B-col (patch) index
  const int hi = lane >> 4;    // k-chunk

  const int c = blockIdx.x / 170;
  const int bc = blockIdx.x - c * 170;

  // ---- T fragments in registers: 2 mf x 8 ks x 16 B = 64 VGPR
  short8 tA0[8], tA1[8];
  {
    const unsigned short* tp = wsT + (size_t)c * 65536 + (size_t)(w * 32 + p) * 256 + hi * 8;
#pragma unroll
    for (int ks = 0; ks < 8; ++ks) tA0[ks] = *(const short8*)(tp + ks * 32);
    tp += 4096;
#pragma unroll
    for (int ks = 0; ks < 8; ++ks) tA1[ks] = *(const short8*)(tp + ks * 32);
  }

  // ---- staging geometry (strip = 1024 float4, 2 per thread; lb1 = lb0+256, g1 = g0+4096)
  const int c40 = t & 63;
  const int r0_ = t >> 6;
  const int p0s = c40 >> 2;
  const int lb0 = p0s * 512 + ((r0_ * 32 + (c40 & 3) * 8) ^ ((p0s & 7) << 4));
  const size_t g0 = (size_t)r0_ * 512 + c40 * 4;

  auto src_base = [&](int s) -> const float* {
    int b_ = s >> 6, t6 = s & 63, ph = t6 >> 1, half = t6 & 1;
    return x + (((size_t)(b_ * 3 + c) * 512 + ph * 16) << 9) + half * 256;
  };
  auto stash = [&](unsigned char* Ab, const float4& fa, const float4& fb) {
    unsigned lo = (unsigned)f2bf(fa.x) | ((unsigned)f2bf(fa.y) << 16);
    unsigned hh = (unsigned)f2bf(fa.z) | ((unsigned)f2bf(fa.w) << 16);
    *(uint2*)(Ab + lb0) = make_uint2(lo, hh);
    lo = (unsigned)f2bf(fb.x) | ((unsigned)f2bf(fb.y) << 16);
    hh = (unsigned)f2bf(fb.z) | ((unsigned)f2bf(fb.w) << 16);
    *(uint2*)(Ab + lb0 + 256) = make_uint2(lo, hh);
  };

  // epilogue geometry: wave w stores patches w and w+8 (offsets +8192/+4096)
  const int sp0 = w;
  const int rso0 = sp0 * 1024 + ((lane * 16) ^ ((sp0 & 7) << 4));
  const int aso0 = sp0 * 512 + ((lane * 8) ^ ((sp0 & 7) << 4));
  float* recp = out + (size_t)25165824;

  const int swz = (p & 7) << 4;
  const unsigned char* bpO = S8 + p * 512;  // + A-buffer offset per iter

  // ---- prologue: strip bc -> A[0]; strip bc+170 -> regs
  float4 pfa, pfb, nfa, nfb;
  nfa = make_float4(0.f, 0.f, 0.f, 0.f); nfb = nfa;
  {
    const float* sb = src_base(bc);
    pfa = *(const float4*)(sb + g0);
    pfb = *(const float4*)(sb + g0 + 4096);
  }
  stash(S8, pfa, pfb);
  {
    const float* sb = src_base(bc + 170);
    pfa = *(const float4*)(sb + g0);
    pfb = *(const float4*)(sb + g0 + 4096);
  }
  __syncthreads();

  int i = 0;
  for (int s = bc; s < 2048; s += 170, ++i) {
    unsigned char* Ac = S8 + (i % 3) * 8192;
    unsigned char* An = S8 + ((i + 1) % 3) * 8192;
    unsigned char* Rc = S8 + 24576 + (i & 1) * 16384;

    // a: issue strip i+2 loads (drained at this iter's barrier, after MFMA+stash+scatter)
    if (s + 340 < 2048) {
      const float* sb = src_base(s + 340);
      nfa = *(const float4*)(sb + g0);
      nfb = *(const float4*)(sb + g0 + 4096);
    }

    // b: MFMA, 4 independent chains
    const unsigned char* bp = Ac + p * 512;
    const f32x4 z = {0.f, 0.f, 0.f, 0.f};
    f32x4 a0a = z, a0b = z, a1a = z, a1b = z;
#pragma unroll
    for (int ks = 0; ks < 4; ++ks) {
      short8 bf = *(const short8*)(bp + ((ks * 64 + hi * 16) ^ swz));
      a0a = __builtin_amdgcn_mfma_f32_16x16x32_bf16(tA0[ks], bf, a0a, 0, 0, 0);
      a1a = __builtin_amdgcn_mfma_f32_16x16x32_bf16(tA1[ks], bf, a1a, 0, 0, 0);
    }
#pragma unroll
    for (int ks = 4; ks < 8; ++ks) {
      short8 bf = *(const short8*)(bp + ((ks * 64 + hi * 16) ^ swz));
      a0b = __builtin_amdgcn_mfma_f32_16x16x32_bf16(tA0[ks], bf, a0b, 0, 0, 0);
      a1b = __builtin_amdgcn_mfma_f32_16x16x32_bf16(tA1[ks], bf, a1b, 0, 0, 0);
    }
    f32x4 acc0 = a0a + a0b;
    f32x4 acc1 = a1a + a1b;

    // c: stash strip i+1 into A[(i+1)%3]
    if (s + 170 < 2048) stash(An, pfa, pfb);

    // d: scatter acc -> R[i&1], swizzled [patch][outcol]
    {
      int oc0 = w * 32 + hi * 4;
      *(f32x4*)(Rc + p * 1024 + ((oc0 * 4) ^ swz)) = acc0;
      *(f32x4*)(Rc + p * 1024 + (((oc0 + 16) * 4) ^ swz)) = acc1;
    }
    __syncthreads();  // the ONLY barrier per strip

    // f: epilogue — wave-contiguous 1 KB/patch stores
    {
      int b_ = s >> 6, t6 = s & 63, ph = t6 >> 1, half = t6 & 1;
      size_t nbase = ((size_t)b_ * 1024 + ph * 32 + half * 16);
      size_t pb = ((nbase + sp0) * 3 + c) << 8;
      {
        f32x4 rv = *(const f32x4*)(Rc + rso0);
        uint2 pv = *(const uint2*)(Ac + aso0);
        float q0 = bf2f((unsigned short)(pv.x & 0xFFFF));
        float q1 = bf2f((unsigned short)(pv.x >> 16));
        float q2 = bf2f((unsigned short)(pv.y & 0xFFFF));
        float q3 = bf2f((unsigned short)(pv.y >> 16));
        *(float4*)(out + pb + lane * 4) =
            make_float4(q0 - rv[0], q1 - rv[1], q2 - rv[2], q3 - rv[3]);
        *(float4*)(recp + pb + lane * 4) = make_float4(rv[0], rv[1], rv[2], rv[3]);
      }
      {
        size_t pb1 = pb + 6144;  // patch sp0+8: +8*3*256 floats
        f32x4 rv = *(const f32x4*)(Rc + rso0 + 8192);
        uint2 pv = *(const uint2*)(Ac + aso0 + 4096);
        float q0 = bf2f((unsigned short)(pv.x & 0xFFFF));
        float q1 = bf2f((unsigned short)(pv.x >> 16));
        float q2 = bf2f((unsigned short)(pv.y & 0xFFFF));
        float q3 = bf2f((unsigned short)(pv.y >> 16));
        *(float4*)(out + pb1 + lane * 4) =
            make_float4(q0 - rv[0], q1 - rv[1], q2 - rv[2], q3 - rv[3]);
        *(float4*)(recp + pb1 + lane * 4) = make_float4(rv[0], rv[1], rv[2], rv[3]);
      }
    }
    pfa = nfa; pfb = nfb;
  }
}

extern "C" void kernel_launch(void* const* d_in, const int* in_sizes, int n_in,
                              void* d_out, int out_size, void* d_ws, size_t ws_size,
                              hipStream_t stream) {
  const float* x  = (const float*)d_in[0];
  const float* w1 = (const float*)d_in[1];
  const float* b1 = (const float*)d_in[2];
  const float* w2 = (const float*)d_in[3];
  const float* b2 = (const float*)d_in[4];
  const float* w3 = (const float*)d_in[5];
  const float* b3 = (const float*)d_in[6];
  float* out = (float*)d_out;

  float* ws = (float*)d_ws;
  float* wsM = ws;                                    // 768 floats
  unsigned short* wsT = (unsigned short*)(ws + 832);  // 3 x 256 x 256 bf16

  mlp_all_kernel<<<1, 1024, 0, stream>>>(w1, b1, w2, b2, w3, b3, wsM,
                                         out + (size_t)50331648);
  build_T_kernel<<<6, 1024, 0, stream>>>(wsM, wsT);
  gemm_main_kernel<<<510, 512, 0, stream>>>(x, wsT, out);
}

// Round 4
// 308.682 us; speedup vs baseline: 1.1889x; 1.1889x over previous
//
#include <hip/hip_runtime.h>

typedef __attribute__((ext_vector_type(8))) short short8;
typedef __attribute__((ext_vector_type(4))) float f32x4;

__device__ __forceinline__ unsigned short f2bf(float f) {
  unsigned u = __float_as_uint(f);
  u += 0x7FFF + ((u >> 16) & 1);
  return (unsigned short)(u >> 16);
}
__device__ __forceinline__ float bf2f(unsigned short h) {
  return __uint_as_float(((unsigned)h) << 16);
}

// ---------------- kernel 1: h2 row-sums (hbar accumulation) ----------------
// grid 8 x 256 (proven: ~5.6 us, LDS work spread over 8 CUs).
__global__ __launch_bounds__(256) void mlp_h2_kernel(
    const float* __restrict__ w1, const float* __restrict__ b1,
    const float* __restrict__ w2, const float* __restrict__ b2,
    float* __restrict__ hbar)
{
  __shared__ float W2T[64][65];
  __shared__ float h1s[32][64];
  __shared__ float partial[4][64];
  const int t = threadIdx.x;
  const int k = t & 63, rg = t >> 6;

  for (int v = 0; v < 16; ++v) {
    int idx = v * 256 + t;
    W2T[idx & 63][idx >> 6] = w2[idx];
  }
  const int r0 = blockIdx.x * 32;
  for (int v = 0; v < 8; ++v) {
    int idx = v * 256 + t;
    int rl = idx >> 6, j = idx & 63;
    int r = r0 + rl;
    float gx = (float)(r >> 4) * (1.0f / 15.0f);
    float gy = (float)(r & 15) * (1.0f / 15.0f);
    float h = gx * w1[2 * j] + gy * w1[2 * j + 1] + b1[j];
    h1s[rl][j] = fmaxf(h, 0.0f);
  }
  __syncthreads();

  float acc[8] = {0, 0, 0, 0, 0, 0, 0, 0};
  for (int j = 0; j < 64; ++j) {
    float w = W2T[j][k];
#pragma unroll
    for (int rr = 0; rr < 8; ++rr)
      acc[rr] += h1s[rg * 8 + rr][j] * w;
  }
  float b2v = b2[k];
  float s = 0.0f;
#pragma unroll
  for (int rr = 0; rr < 8; ++rr) s += fmaxf(acc[rr] + b2v, 0.0f);
  partial[rg][k] = s;
  __syncthreads();
  if (t < 64) {
    atomicAdd(&hbar[t], partial[0][t] + partial[1][t] + partial[2][t] + partial[3][t]);
  }
}

// ---------------- kernel 2: Mf (inline) + build fused per-channel operator T ----
// grid 6 x 1024: block = (channel, oc-half). Computes Mf for its channel from
// hbar (64-FMA dot per thread, trivial), then T as before. bh==0 writes outMf.
__global__ __launch_bounds__(1024) void build_TM_kernel(
    const float* __restrict__ hbar, const float* __restrict__ w3,
    const float* __restrict__ b3, unsigned short* __restrict__ wsT,
    float* __restrict__ outMf)
{
  __shared__ float Dl[16][16];
  __shared__ float Ml[256];
  __shared__ float Gl[16][16][16];
  const int t = threadIdx.x;
  const int c = blockIdx.x >> 1;
  const int bh = blockIdx.x & 1;

  if (t < 256) {
    int i = t >> 4, k = t & 15;
    float sc = (i == 0) ? 0.25f : 0.35355339059327373f;
    Dl[i][k] = sc * cosf(3.14159265358979323846f * (float)((2 * i + 1) * k) * (1.0f / 32.0f));
    // inline Mf: j = c*256 + t
    int j = c * 256 + t;
    float s = 0.f;
    for (int kk = 0; kk < 64; ++kk) s += hbar[kk] * w3[j * 64 + kk];
    float o = b3[j] + s * (1.0f / 256.0f);
    float m = 1.0f / (1.0f + expf(-o));
    Ml[t] = m;
    if (bh == 0) outMf[j] = m;
  }
  __syncthreads();

  for (int e = t; e < 4096; e += 1024) {
    int i = e >> 8, ss = (e >> 4) & 15, v = e & 15;
    float g = 0.f;
#pragma unroll
    for (int l = 0; l < 16; ++l)
      g += Ml[i * 16 + l] * Dl[l][ss] * Dl[l][v];
    Gl[i][ss][v] = g;
  }
  __syncthreads();

  const int oc = bh * 128 + (t >> 3);
  const int jsel = t & 7;
  const int r = oc >> 4, ss = oc & 15;
  const int j0 = jsel * 2, j1 = j0 + 1;
  float a0[16], a1[16];
#pragma unroll
  for (int k = 0; k < 16; ++k) { a0[k] = 0.f; a1[k] = 0.f; }
  for (int i = 0; i < 16; ++i) {
    float wr = Dl[i][r];
    float G16[16];
    const float* gp = &Gl[i][ss][0];
#pragma unroll
    for (int k = 0; k < 16; ++k) G16[k] = gp[k];
    float w0 = wr * Dl[i][j0];
    float w1v = wr * Dl[i][j1];
#pragma unroll
    for (int k = 0; k < 16; ++k) { a0[k] += w0 * G16[k]; a1[k] += w1v * G16[k]; }
  }
  unsigned short* dst = wsT + (size_t)c * 65536 + (size_t)oc * 256;
  unsigned* d0 = (unsigned*)(dst + j0 * 16);
  unsigned* d1 = (unsigned*)(dst + j1 * 16);
#pragma unroll
  for (int k = 0; k < 8; ++k)
    d0[k] = (unsigned)f2bf(a0[2 * k]) | ((unsigned)f2bf(a0[2 * k + 1]) << 16);
#pragma unroll
  for (int k = 0; k < 8; ++k)
    d1[k] = (unsigned)f2bf(a1[2 * k]) | ((unsigned)f2bf(a1[2 * k + 1]) << 16);
}

// ---------------- main kernel: streaming GEMM + LDS-transposed epilogue ----------
// R2-proven loop (3 barriers, 24 KB LDS). New: XCD-trio blockIdx remap so the
// 3 channel-blocks of the same spatial strip share an XCD (merged write windows).
__global__ __launch_bounds__(512, 4) void gemm_main_kernel(
    const float* __restrict__ x, const unsigned short* __restrict__ wsT,
    float* __restrict__ out)
{
  __shared__ uint4 AldsV[512];    // 8 KB: 16 patches x 512 B (bf16), swizzled
  __shared__ float recB[4096];    // 16 KB: 16 patches x 256 f32, swizzled
  unsigned char* A8 = (unsigned char*)AldsV;
  unsigned char* R8 = (unsigned char*)recB;
  const int t = threadIdx.x;
  const int lane = t & 63;
  const int w = t >> 6;
  const int p = lane & 15;
  const int hi = lane >> 4;

  // XCD-trio remap: bid, bid+8, bid+16 (same XCD, round-robin over 8) are the
  // 3 channels of the same spatial strip column.
  const int bid = blockIdx.x;
  int c, bc;
  if (bid < 504) {
    bc = (bid / 24) * 8 + (bid & 7);
    c = (bid % 24) >> 3;
  } else {
    int idx = bid - 504;          // 0..5
    bc = 168 + idx / 3;
    c = idx % 3;
  }

  // ---- T fragments in registers: 2 mf x 8 ks x 16 B = 64 VGPR
  short8 tA0[8], tA1[8];
  {
    const unsigned short* tp = wsT + (size_t)c * 65536 + (size_t)(w * 32 + p) * 256 + hi * 8;
#pragma unroll
    for (int ks = 0; ks < 8; ++ks) tA0[ks] = *(const short8*)(tp + ks * 32);
    tp += 4096;
#pragma unroll
    for (int ks = 0; ks < 8; ++ks) tA1[ks] = *(const short8*)(tp + ks * 32);
  }

  // ---- staging geometry (strip = 1024 float4, 2 per thread)
  const int f1 = t + 512;
  const int r0_ = t >> 6, c40 = t & 63;
  const int r1_ = f1 >> 6, c41 = f1 & 63;
  const int p0s = c40 >> 2, p1s = c41 >> 2;
  const int lb0 = p0s * 512 + ((r0_ * 32 + (c40 & 3) * 8) ^ ((p0s & 7) << 4));
  const int lb1 = p1s * 512 + ((r1_ * 32 + (c41 & 3) * 8) ^ ((p1s & 7) << 4));
  const size_t g0 = (size_t)r0_ * 512 + c40 * 4;
  const size_t g1 = (size_t)r1_ * 512 + c41 * 4;

  auto src_base = [&](int s) -> const float* {
    int b_ = s >> 6, t6 = s & 63, ph = t6 >> 1, half = t6 & 1;
    return x + (((size_t)(b_ * 3 + c) * 512 + ph * 16) << 9) + half * 256;
  };

  float4 pfa, pfb;
  {
    const float* sb = src_base(bc);
    pfa = *(const float4*)(sb + g0);
    pfb = *(const float4*)(sb + g1);
  }

  const unsigned char* bp = A8 + p * 512;
  const int swz = (p & 7) << 4;

  // epilogue geometry: wave w reads patches w and w+8
  const int sp0 = w, sp1 = w + 8;
  const int sq = lane;
  const unsigned char* rb0 = R8 + sp0 * 1024;
  const unsigned char* rb1 = R8 + sp1 * 1024;
  const unsigned char* ab0 = A8 + sp0 * 512;
  const unsigned char* ab1 = A8 + sp1 * 512;
  const int rswz0 = (sq * 16) ^ ((sp0 & 7) << 4);
  const int rswz1 = (sq * 16) ^ ((sp1 & 7) << 4);
  const int aswz0 = (sq * 8) ^ ((sp0 & 7) << 4);
  const int aswz1 = (sq * 8) ^ ((sp1 & 7) << 4);

  float* recp = out + (size_t)25165824;

  for (int s = bc; s < 2048; s += 170) {
    const int sn = s + 170;
    __syncthreads();  // prev strip's LDS reads complete
    // issue next-strip loads first (max slack before barrier2 drain)
    float4 na = make_float4(0.f, 0.f, 0.f, 0.f);
    float4 nb = make_float4(0.f, 0.f, 0.f, 0.f);
    if (sn < 2048) {
      const float* sb = src_base(sn);
      na = *(const float4*)(sb + g0);
      nb = *(const float4*)(sb + g1);
    }
    // write current strip to A-LDS (bf16, XOR-swizzled)
    {
      unsigned lo = (unsigned)f2bf(pfa.x) | ((unsigned)f2bf(pfa.y) << 16);
      unsigned hh = (unsigned)f2bf(pfa.z) | ((unsigned)f2bf(pfa.w) << 16);
      *(uint2*)(A8 + lb0) = make_uint2(lo, hh);
      lo = (unsigned)f2bf(pfb.x) | ((unsigned)f2bf(pfb.y) << 16);
      hh = (unsigned)f2bf(pfb.z) | ((unsigned)f2bf(pfb.w) << 16);
      *(uint2*)(A8 + lb1) = make_uint2(lo, hh);
    }
    __syncthreads();  // A ready

    const f32x4 zero4 = {0.f, 0.f, 0.f, 0.f};
    f32x4 acc0 = zero4, acc1 = zero4;
#pragma unroll
    for (int ks = 0; ks < 8; ++ks) {
      short8 bf = *(const short8*)(bp + ((ks * 64 + hi * 16) ^ swz));
      acc0 = __builtin_amdgcn_mfma_f32_16x16x32_bf16(tA0[ks], bf, acc0, 0, 0, 0);
      acc1 = __builtin_amdgcn_mfma_f32_16x16x32_bf16(tA1[ks], bf, acc1, 0, 0, 0);
    }

    // scatter acc -> rec LDS [patch p][outcol], swizzled
    {
      int oc0 = w * 32 + hi * 4;
      int oc1 = oc0 + 16;
      *(f32x4*)(R8 + p * 1024 + ((oc0 * 4) ^ swz)) = acc0;
      *(f32x4*)(R8 + p * 1024 + ((oc1 * 4) ^ swz)) = acc1;
    }
    __syncthreads();  // rec ready

    // store phase: wave w -> patches w, w+8; 1 KB contiguous per patch per array
    {
      int b_ = s >> 6, t6 = s & 63, ph = t6 >> 1, half = t6 & 1;
      size_t nbase = ((size_t)b_ * 1024 + ph * 32 + half * 16);
      {
        size_t pb = ((nbase + sp0) * 3 + c) << 8;
        f32x4 rv = *(const f32x4*)(rb0 + rswz0);
        uint2 pv = *(const uint2*)(ab0 + aswz0);
        float q0 = bf2f((unsigned short)(pv.x & 0xFFFF));
        float q1 = bf2f((unsigned short)(pv.x >> 16));
        float q2 = bf2f((unsigned short)(pv.y & 0xFFFF));
        float q3 = bf2f((unsigned short)(pv.y >> 16));
        *(float4*)(out + pb + sq * 4) =
            make_float4(q0 - rv[0], q1 - rv[1], q2 - rv[2], q3 - rv[3]);
        *(float4*)(recp + pb + sq * 4) = make_float4(rv[0], rv[1], rv[2], rv[3]);
      }
      {
        size_t pb = ((nbase + sp1) * 3 + c) << 8;
        f32x4 rv = *(const f32x4*)(rb1 + rswz1);
        uint2 pv = *(const uint2*)(ab1 + aswz1);
        float q0 = bf2f((unsigned short)(pv.x & 0xFFFF));
        float q1 = bf2f((unsigned short)(pv.x >> 16));
        float q2 = bf2f((unsigned short)(pv.y & 0xFFFF));
        float q3 = bf2f((unsigned short)(pv.y >> 16));
        *(float4*)(out + pb + sq * 4) =
            make_float4(q0 - rv[0], q1 - rv[1], q2 - rv[2], q3 - rv[3]);
        *(float4*)(recp + pb + sq * 4) = make_float4(rv[0], rv[1], rv[2], rv[3]);
      }
    }
    pfa = na; pfb = nb;
  }
}

extern "C" void kernel_launch(void* const* d_in, const int* in_sizes, int n_in,
                              void* d_out, int out_size, void* d_ws, size_t ws_size,
                              hipStream_t stream) {
  const float* x  = (const float*)d_in[0];
  const float* w1 = (const float*)d_in[1];
  const float* b1 = (const float*)d_in[2];
  const float* w2 = (const float*)d_in[3];
  const float* b2 = (const float*)d_in[4];
  const float* w3 = (const float*)d_in[5];
  const float* b3 = (const float*)d_in[6];
  float* out = (float*)d_out;

  float* ws = (float*)d_ws;
  float* hbar = ws + 768;                             // 64 floats
  unsigned short* wsT = (unsigned short*)(ws + 832);  // 3 x 256 x 256 bf16

  hipMemsetAsync(hbar, 0, 64 * sizeof(float), stream);
  mlp_h2_kernel<<<8, 256, 0, stream>>>(w1, b1, w2, b2, hbar);
  build_TM_kernel<<<6, 1024, 0, stream>>>(hbar, w3, b3, wsT,
                                          out + (size_t)50331648);
  gemm_main_kernel<<<510, 512, 0, stream>>>(x, wsT, out);
}